// Round 8
// baseline (3273.792 us; speedup 1.0000x reference)
//
#include <hip/hip_runtime.h>

#define NN     100000
#define NP     100096   // padded to multiple of 128
#define HD     128
#define NE     400000
#define TOT    2400000  // 6 * NE
#define L6P    (NP * 6) // per (node,type) counts, padded
#define NLAYER 8
#define SCHUNK 2048

typedef unsigned short ushort_t;
typedef unsigned int   uint_t;

typedef __bf16 bf16x8 __attribute__((ext_vector_type(8)));
typedef float  f32x4  __attribute__((ext_vector_type(4)));

__device__ __forceinline__ f32x4 mfma16(bf16x8 a, bf16x8 b, f32x4 c) {
  return __builtin_amdgcn_mfma_f32_16x16x32_bf16(a, b, c, 0, 0, 0);
}

__device__ __forceinline__ unsigned short f2bf(float f) {
  unsigned int u = __builtin_bit_cast(unsigned int, f);
  u = (u + 0x7FFFu + ((u >> 16) & 1u)) >> 16;
  return (unsigned short)u;
}
__device__ __forceinline__ float bflo(uint_t v) { return __builtin_bit_cast(float, v << 16); }
__device__ __forceinline__ float bfhi(uint_t v) { return __builtin_bit_cast(float, v & 0xFFFF0000u); }
__device__ __forceinline__ float bf2f(ushort_t v) { return __builtin_bit_cast(float, (uint_t)v << 16); }
__device__ __forceinline__ uint_t packbf(float x, float y) {
  return (uint_t)f2bf(x) | ((uint_t)f2bf(y) << 16);
}

// aux=0: default cached; aux=2: NT (evict-first) for streamed-once data
#define GLOAD_LDS16(g, l) __builtin_amdgcn_global_load_lds( \
    (__attribute__((address_space(1))) void*)(g),           \
    (__attribute__((address_space(3))) void*)(l), 16, 0, 0)
#define GLOAD_LDS16NT(g, l) __builtin_amdgcn_global_load_lds( \
    (__attribute__((address_space(1))) void*)(g),             \
    (__attribute__((address_space(3))) void*)(l), 16, 0, 2)

// ---------- setup kernels (once per call) ----------

__global__ __launch_bounds__(256) void k_init(const float* __restrict__ ns,
    float* __restrict__ oh, float* __restrict__ oold, ushort_t* __restrict__ hbf) {
  int i = blockIdx.x * 256 + threadIdx.x;
  if (i < NN * HD) {
    float v = ns[i];
    oh[i] = v; oold[i] = v; hbf[i] = f2bf(v);
  }
}

__global__ __launch_bounds__(256) void k_prep(const float* __restrict__ Wm,
    const float* __restrict__ wih, const float* __restrict__ whh,
    ushort_t* __restrict__ Wcat, ushort_t* __restrict__ wihb, ushort_t* __restrict__ whhb) {
  int t = blockIdx.x * 256 + threadIdx.x;
  if (t < 128 * 768) {
    int n = t / 768, k = t % 768;
    int e = k >> 7, d = k & 127;
    Wcat[t] = f2bf(Wm[(e * 128 + d) * 128 + n]);   // [n][k], N-major
  }
  if (t < 384 * 128) {
    wihb[t] = f2bf(wih[t]);
    whhb[t] = f2bf(whh[t]);
  }
}

// direct histogram: atomics spread over 600k counters (avg 4/addr -> no contention)
__global__ __launch_bounds__(256) void k_hist(const int* __restrict__ edges, int* __restrict__ cnt6) {
  int t = blockIdx.x * 256 + threadIdx.x;
  if (t >= TOT) return;
  int e = t / NE, m = t - e * NE;
  int tgt;
  if (e < 3) tgt = edges[(e * NE + m) * 2 + 1];
  else       tgt = edges[((e - 3) * NE + m) * 2];
  atomicAdd(&cnt6[tgt * 6 + e], 1);
}

__global__ __launch_bounds__(256) void k_div(const int* __restrict__ cnt6,
    float* __restrict__ divf) {
  int i = blockIdx.x * 256 + threadIdx.x;
  if (i < NP) {
    int c = 0;
#pragma unroll
    for (int e = 0; e < 6; e++) c += cnt6[i * 6 + e];
    divf[i] = c ? (float)c : 1.0f;
  }
}

// exclusive scan over cnt6 (length L6P) -> offs6
__global__ __launch_bounds__(256) void k_scan1(const int* __restrict__ cnt, int* __restrict__ bsum) {
  int base = blockIdx.x * SCHUNK + threadIdx.x * 8;
  int s = 0;
#pragma unroll
  for (int j = 0; j < 8; j++) { int idx = base + j; s += (idx < L6P) ? cnt[idx] : 0; }
  for (int o = 32; o > 0; o >>= 1) s += __shfl_down(s, o);
  __shared__ int sm[4];
  if ((threadIdx.x & 63) == 0) sm[threadIdx.x >> 6] = s;
  __syncthreads();
  if (threadIdx.x == 0) bsum[blockIdx.x] = sm[0] + sm[1] + sm[2] + sm[3];
}

__global__ __launch_bounds__(512) void k_scan2(int* __restrict__ bsum, int nb) { // 1 block, nb<=512
  int t = threadIdx.x, lane = t & 63, wv = t >> 6;
  int orig = (t < nb) ? bsum[t] : 0;
  int v = orig;
  for (int o = 1; o < 64; o <<= 1) { int x = __shfl_up(v, o); if (lane >= o) v += x; }
  __shared__ int ws[8];
  if (lane == 63) ws[wv] = v;
  __syncthreads();
  int add = 0;
  for (int w = 0; w < wv; w++) add += ws[w];
  if (t < nb) bsum[t] = v - orig + add;   // exclusive
}

__global__ __launch_bounds__(256) void k_scan3(const int* __restrict__ cnt,
    const int* __restrict__ bsum, int* __restrict__ offs) {
  int base = blockIdx.x * SCHUNK + threadIdx.x * 8;
  int vals[8], pre[8];
  int s = 0;
#pragma unroll
  for (int j = 0; j < 8; j++) {
    int idx = base + j;
    vals[j] = (idx < L6P) ? cnt[idx] : 0;
    pre[j] = s; s += vals[j];
  }
  int lane = threadIdx.x & 63, wvi = threadIdx.x >> 6;
  int v = s;
  for (int o = 1; o < 64; o <<= 1) { int t = __shfl_up(v, o); if (lane >= o) v += t; }
  __shared__ int wsum[4];
  if (lane == 63) wsum[wvi] = v;
  __syncthreads();
  int wpre = 0;
  for (int w = 0; w < wvi; w++) wpre += wsum[w];
  int texcl = (v - s) + wpre + bsum[blockIdx.x];
#pragma unroll
  for (int j = 0; j < 8; j++) {
    int idx = base + j;
    if (idx < L6P) {
      offs[idx] = texcl + pre[j];
      if (idx == L6P - 1) offs[L6P] = texcl + pre[j] + vals[j];
    }
  }
}

// direct CSR fill (cursor atomics spread over 600k addresses)
__global__ __launch_bounds__(256) void k_fill(const int* __restrict__ edges,
    int* __restrict__ cursor6, int* __restrict__ entries) {
  int t = blockIdx.x * 256 + threadIdx.x;
  if (t >= TOT) return;
  int e = t / NE, m = t - e * NE;
  int src, tgt;
  if (e < 3) { int b = (e * NE + m) * 2;       src = edges[b];     tgt = edges[b + 1]; }
  else       { int b = ((e - 3) * NE + m) * 2; src = edges[b + 1]; tgt = edges[b]; }
  int pos = atomicAdd(&cursor6[tgt * 6 + e], 1);
  entries[pos] = src;   // type implied by segment
}

// ---------- per-layer kernels ----------

// Wave-per-(node,type) CSR aggregation: 600k waves, scalarized edge stream
// (readlane -> SALU addr), 8 gathers in flight. agg stream NT (evict-first)
// so the hbf gather table stays L3-resident.
__global__ __launch_bounds__(512) void k_agg(const ushort_t* __restrict__ hbf,
    const int* __restrict__ offs6, const int* __restrict__ entries,
    ushort_t* __restrict__ agg, int node0, int rows) {
  int lane = threadIdx.x & 63, wv = threadIdx.x >> 6;
  int segl = blockIdx.x * 8 + wv;            // local segment = node_local*6 + e
  if (segl >= rows * 6) return;
  int gseg = node0 * 6 + segl;               // global (node,type) segment
  int S = offs6[gseg], E = offs6[gseg + 1];
  float cx = 0.f, cy = 0.f;
  int voff = lane * 4;
  const char* hb = (const char*)hbf;
  for (int c0 = S; c0 < E; c0 += 64) {
    int m = E - c0; if (m > 64) m = 64;
    int ent = __builtin_nontemporal_load(entries + c0 + (lane < m ? lane : 0));
    for (int j = 0; j < m; j += 8) {
      int s_[8];
      uint_t v[8];
#pragma unroll
      for (int u = 0; u < 8; u++) {
        int jj = (j + u < m) ? j + u : m - 1;
        s_[u] = __builtin_amdgcn_readlane(ent, jj);
      }
#pragma unroll
      for (int u = 0; u < 8; u++)
        v[u] = *(const uint_t*)(hb + ((size_t)(uint_t)s_[u] << 8) + voff);
      cx += bflo(v[0]); cy += bfhi(v[0]);
#pragma unroll
      for (int u = 1; u < 8; u++)
        if (j + u < m) { cx += bflo(v[u]); cy += bfhi(v[u]); }
    }
  }
  // agg row = node_local (768 ushorts), k-block = e*128 + dims
  uint_t* outp = (uint_t*)(agg + (size_t)segl * 128);
  __builtin_nontemporal_store(packbf(cx, cy), outp + lane);
}

// Fused msgs-GEMM + GRU. Block = 128 nodes, 8 waves, 64KB LDS.
// Phase A: msgs = (agg@Wcat + sum_e cnt_e*b_msg_e)/div + 1e-8 -> swizzled Mlds.
// Phase B: gates = [msgs|h] x [wih|whh], GRU math, write new h (bf16) to hbfout.
// All LDS tiles XOR-swizzled (byte ^= (row&7)<<4); gload_lds uses pre-swizzled src.
// launch_bounds (512,2): VGPR cap 256 -> NO spill (r7 had 64 VGPR + 154MB scratch).
__global__ __launch_bounds__(512, 2) void k_fused(
    const ushort_t* __restrict__ agg, const ushort_t* __restrict__ Wcat,
    const int* __restrict__ cnt6, const float* __restrict__ divf,
    const float* __restrict__ b_msg, const ushort_t* __restrict__ hbfin,
    const ushort_t* __restrict__ wihb, const ushort_t* __restrict__ whhb,
    const float* __restrict__ b_ih, const float* __restrict__ b_hh,
    float* __restrict__ hf, ushort_t* __restrict__ hbfout,
    int node0, int last) {
  __shared__ char smem[65536];
  char* Alds = smem;             // 16KB (phase A), 128 rows x 128B
  char* Blds = smem + 16384;     // 16KB (phase A)
  char* Mlds = smem + 32768;     // 32KB msgs tile, 128 rows x 256B
  char* Hlds = smem;             // 32KB h tile (phase B, reuses A/B)
  int lane = threadIdx.x & 63, wv = threadIdx.x >> 6;
  int wr = wv >> 1, wc = wv & 1;
  int rbase = blockIdx.x * 128;

  // ---- phase A ----
  f32x4 acc[2][4] = {};
  for (int k0 = 0; k0 < 768; k0 += 64) {
#pragma unroll
    for (int i = 0; i < 2; i++) {
      int base = i * 8192 + wv * 1024;
      int q = base + lane * 16;
      int row = q >> 7;
      int colb = (q & 127) ^ ((row & 7) << 4);
      GLOAD_LDS16NT(agg + (size_t)(rbase + row) * 768 + k0 + (colb >> 1), Alds + base);
      GLOAD_LDS16(Wcat + (size_t)row * 768 + k0 + (colb >> 1), Blds + base);
    }
    __syncthreads();
#pragma unroll
    for (int kk = 0; kk < 2; kk++) {
      bf16x8 af[2], bv[4];
#pragma unroll
      for (int m = 0; m < 2; m++) {
        int row = wr * 32 + m * 16 + (lane & 15);
        int b = ((row << 7) + kk * 64 + ((lane >> 4) << 4)) ^ ((row & 7) << 4);
        af[m] = *(const bf16x8*)(Alds + b);
      }
#pragma unroll
      for (int nf = 0; nf < 4; nf++) {
        int row = wc * 64 + nf * 16 + (lane & 15);
        int b = ((row << 7) + kk * 64 + ((lane >> 4) << 4)) ^ ((row & 7) << 4);
        bv[nf] = *(const bf16x8*)(Blds + b);
      }
#pragma unroll
      for (int m = 0; m < 2; m++)
#pragma unroll
        for (int nf = 0; nf < 4; nf++)
          acc[m][nf] = mfma16(af[m], bv[nf], acc[m][nf]);
    }
    __syncthreads();
  }
  // issue h-tile staging (overwrites Alds/Blds; all phase-A reads are done)
#pragma unroll
  for (int i = 0; i < 4; i++) {
    int base = i * 8192 + wv * 1024;
    int q = base + lane * 16;
    int row = q >> 8;
    int colb = (q & 255) ^ ((row & 7) << 4);
    GLOAD_LDS16(hbfin + (size_t)(node0 + rbase + row) * HD + (colb >> 1), Hlds + base);
  }
  // epilogue: msgs -> Mlds (swizzled); overlaps the h-tile load latency
#pragma unroll
  for (int m = 0; m < 2; m++) {
#pragma unroll
    for (int r = 0; r < 4; r++) {
      int rloc = wr * 32 + m * 16 + (lane >> 4) * 4 + r;
      int node = node0 + rbase + rloc;   // divf/cnt6 are NP-sized: pads -> c=0, div=1
      float dv = divf[node];
      const int* c6 = cnt6 + (size_t)node * 6;
      int c[6];
#pragma unroll
      for (int e = 0; e < 6; e++) c[e] = c6[e];
#pragma unroll
      for (int nf = 0; nf < 4; nf++) {
        int col = wc * 64 + nf * 16 + (lane & 15);
        float badd = 0.f;
#pragma unroll
        for (int e = 0; e < 6; e++) badd += (float)c[e] * b_msg[e * 128 + col];
        float v = (acc[m][nf][r] + badd) / dv + 1e-8f;
        int b = ((rloc << 8) + col * 2) ^ ((rloc & 7) << 4);
        *(ushort_t*)(Mlds + b) = f2bf(v);
      }
    }
  }
  __syncthreads();   // Mlds visible + Hlds loaded (vmcnt drained at barrier)

  // ---- phase B: GRU, 4 rounds x 32 rows ----
  int d = wv * 16 + (lane & 15);
  float bir = b_ih[d],       bhr = b_hh[d];
  float biz = b_ih[128 + d], bhz = b_hh[128 + d];
  float bin = b_ih[256 + d], bhn = b_hh[256 + d];
#pragma unroll
  for (int rd = 0; rd < 4; rd++) {
    f32x4 acb[2][6] = {};
#pragma unroll
    for (int ks = 0; ks < 4; ks++) {
      bf16x8 am[2], ah[2];
#pragma unroll
      for (int m = 0; m < 2; m++) {
        int row = rd * 32 + m * 16 + (lane & 15);
        int b = ((row << 8) + ks * 64 + ((lane >> 4) << 4)) ^ ((row & 7) << 4);
        am[m] = *(const bf16x8*)(Mlds + b);
        ah[m] = *(const bf16x8*)(Hlds + b);
      }
      bf16x8 bi[3], bh[3];
#pragma unroll
      for (int g = 0; g < 3; g++) {
        int nidx = g * 128 + d;
        int ko = ks * 32 + ((lane >> 4) << 3);
        bi[g] = *(const bf16x8*)(wihb + (size_t)nidx * HD + ko);
        bh[g] = *(const bf16x8*)(whhb + (size_t)nidx * HD + ko);
      }
#pragma unroll
      for (int m = 0; m < 2; m++)
#pragma unroll
        for (int g = 0; g < 3; g++) {
          acb[m][g]     = mfma16(am[m], bi[g], acb[m][g]);
          acb[m][3 + g] = mfma16(ah[m], bh[g], acb[m][3 + g]);
        }
    }
#pragma unroll
    for (int m = 0; m < 2; m++) {
#pragma unroll
      for (int r = 0; r < 4; r++) {
        int rloc = rd * 32 + m * 16 + (lane >> 4) * 4 + r;
        int row = node0 + rbase + rloc;
        if (row < NN) {
          float ir = acb[m][0][r], iz = acb[m][1][r], in = acb[m][2][r];
          float hr = acb[m][3][r], hz = acb[m][4][r], hn = acb[m][5][r];
          float rg = 1.f / (1.f + expf(-(ir + hr + bir + bhr)));
          float zg = 1.f / (1.f + expf(-(iz + hz + biz + bhz)));
          float ng = tanhf(in + bin + rg * (hn + bhn));
          int hb = ((rloc << 8) + d * 2) ^ ((rloc & 7) << 4);
          float hold = bf2f(*(const ushort_t*)(Hlds + hb));
          float o = (1.f - zg) * ng + zg * hold;
          size_t idx = (size_t)row * HD + d;
          hbfout[idx] = f2bf(o);
          if (last) hf[idx] = o;
        }
      }
    }
  }
}

// ---------- host ----------

extern "C" void kernel_launch(void* const* d_in, const int* in_sizes, int n_in,
                              void* d_out, int out_size, void* d_ws, size_t ws_size,
                              hipStream_t stream) {
  const float* node_states = (const float*)d_in[0];
  const int*   edges       = (const int*)d_in[1];
  const float* W_msg       = (const float*)d_in[2];
  const float* b_msg       = (const float*)d_in[3];
  const float* w_ih        = (const float*)d_in[4];
  const float* w_hh        = (const float*)d_in[5];
  const float* b_ih        = (const float*)d_in[6];
  const float* b_hh        = (const float*)d_in[7];
  float* out_h   = (float*)d_out;
  float* out_old = out_h + (size_t)NN * HD;

  char* p = (char*)d_ws;
  auto carve = [&](size_t bytes) { char* r = p; p += (bytes + 255) & ~(size_t)255; return r; };
  ushort_t* hbfA  = (ushort_t*)carve((size_t)NP * HD * 2);
  ushort_t* hbfB  = (ushort_t*)carve((size_t)NP * HD * 2);
  ushort_t* Wcat  = (ushort_t*)carve((size_t)128 * 768 * 2);
  ushort_t* wihb  = (ushort_t*)carve((size_t)384 * 128 * 2);
  ushort_t* whhb  = (ushort_t*)carve((size_t)384 * 128 * 2);
  int*   cnt6     = (int*)carve((size_t)L6P * 4);
  float* divf     = (float*)carve((size_t)NP * 4);
  int*   offs6    = (int*)carve((size_t)(L6P + 1) * 4);
  int*   cursor6  = (int*)carve((size_t)L6P * 4);
  int*   entries  = (int*)carve((size_t)TOT * 4);
  int*   bsum     = (int*)carve(512 * 4);
  size_t used  = (size_t)(p - (char*)d_ws);
  size_t avail = ws_size > used ? ws_size - used : 0;
  size_t chunk_rows = avail / (768 * 2);
  if (chunk_rows > (size_t)NP) chunk_rows = NP;
  chunk_rows &= ~(size_t)127;
  if (chunk_rows < 128) chunk_rows = 128;
  ushort_t* agg = (ushort_t*)p;

  hipMemsetAsync(cnt6, 0, (size_t)L6P * 4, stream);
  hipMemsetAsync(hbfA + (size_t)NN * HD, 0, (size_t)(NP - NN) * HD * 2, stream);
  hipMemsetAsync(hbfB + (size_t)NN * HD, 0, (size_t)(NP - NN) * HD * 2, stream);

  k_init<<<(NN * HD + 255) / 256, 256, 0, stream>>>(node_states, out_h, out_old, hbfA);
  k_prep<<<(128 * 768 + 255) / 256, 256, 0, stream>>>(W_msg, w_ih, w_hh, Wcat, wihb, whhb);
  k_hist<<<(TOT + 255) / 256, 256, 0, stream>>>(edges, cnt6);
  k_div<<<(NP + 255) / 256, 256, 0, stream>>>(cnt6, divf);
  int nb = (L6P + SCHUNK - 1) / SCHUNK;   // 294
  k_scan1<<<nb, 256, 0, stream>>>(cnt6, bsum);
  k_scan2<<<1, 512, 0, stream>>>(bsum, nb);
  k_scan3<<<nb, 256, 0, stream>>>(cnt6, bsum, offs6);
  hipMemcpyAsync(cursor6, offs6, (size_t)L6P * 4, hipMemcpyDeviceToDevice, stream);
  k_fill<<<(TOT + 255) / 256, 256, 0, stream>>>(edges, cursor6, entries);

  ushort_t* hA = hbfA;
  ushort_t* hB = hbfB;
  for (int L = 0; L < NLAYER; L++) {
    int last = (L == NLAYER - 1);
    for (size_t n0 = 0; n0 < (size_t)NP; n0 += chunk_rows) {
      int rows = (int)(((size_t)NP - n0) < chunk_rows ? ((size_t)NP - n0) : chunk_rows);
      k_agg<<<(rows * 6 + 7) / 8, 512, 0, stream>>>(hA, offs6, entries, agg, (int)n0, rows);
      k_fused<<<rows / 128, 512, 0, stream>>>(agg, Wcat, cnt6, divf, b_msg, hA,
                                              wihb, whhb, b_ih, b_hh,
                                              out_h, hB, (int)n0, last);
    }
    ushort_t* tmp = hA; hA = hB; hB = tmp;
  }
}

// Round 9
// 2856.773 us; speedup vs baseline: 1.1460x; 1.1460x over previous
//
#include <hip/hip_runtime.h>

#define NN     100000
#define NP     100096   // padded to multiple of 128
#define HD     128
#define NE     400000
#define TOT    2400000  // 6 * NE
#define L6P    (NP * 6) // per (node,type) counts, padded
#define NLAYER 8
#define SCHUNK 2048
#define CHROWS 25088    // layer-pipeline chunk (agg chunk = 38.5 MB, L3-resident)

typedef unsigned short ushort_t;
typedef unsigned int   uint_t;

typedef __bf16 bf16x8 __attribute__((ext_vector_type(8)));
typedef float  f32x4  __attribute__((ext_vector_type(4)));

__device__ __forceinline__ f32x4 mfma16(bf16x8 a, bf16x8 b, f32x4 c) {
  return __builtin_amdgcn_mfma_f32_16x16x32_bf16(a, b, c, 0, 0, 0);
}

__device__ __forceinline__ unsigned short f2bf(float f) {
  unsigned int u = __builtin_bit_cast(unsigned int, f);
  u = (u + 0x7FFFu + ((u >> 16) & 1u)) >> 16;
  return (unsigned short)u;
}
__device__ __forceinline__ float bflo(uint_t v) { return __builtin_bit_cast(float, v << 16); }
__device__ __forceinline__ float bfhi(uint_t v) { return __builtin_bit_cast(float, v & 0xFFFF0000u); }
__device__ __forceinline__ float bf2f(ushort_t v) { return __builtin_bit_cast(float, (uint_t)v << 16); }
__device__ __forceinline__ uint_t packbf(float x, float y) {
  return (uint_t)f2bf(x) | ((uint_t)f2bf(y) << 16);
}

#define GLOAD_LDS16(g, l) __builtin_amdgcn_global_load_lds( \
    (__attribute__((address_space(1))) void*)(g),           \
    (__attribute__((address_space(3))) void*)(l), 16, 0, 0)

// ---------- setup kernels (once per call) ----------

__global__ __launch_bounds__(256) void k_init(const float* __restrict__ ns,
    float* __restrict__ oh, float* __restrict__ oold, ushort_t* __restrict__ hbf) {
  int i = blockIdx.x * 256 + threadIdx.x;
  if (i < NN * HD) {
    float v = ns[i];
    oh[i] = v; oold[i] = v; hbf[i] = f2bf(v);
  }
}

__global__ __launch_bounds__(256) void k_prep(const float* __restrict__ Wm,
    const float* __restrict__ wih, const float* __restrict__ whh,
    ushort_t* __restrict__ Wcat, ushort_t* __restrict__ wihb, ushort_t* __restrict__ whhb) {
  int t = blockIdx.x * 256 + threadIdx.x;
  if (t < 128 * 768) {
    int n = t / 768, k = t % 768;
    int e = k >> 7, d = k & 127;
    Wcat[t] = f2bf(Wm[(e * 128 + d) * 128 + n]);   // [n][k], N-major
  }
  if (t < 384 * 128) {
    wihb[t] = f2bf(wih[t]);
    whhb[t] = f2bf(whh[t]);
  }
}

// direct histogram: atomics spread over 600k counters (avg 4/addr -> no contention)
__global__ __launch_bounds__(256) void k_hist(const int* __restrict__ edges, int* __restrict__ cnt6) {
  int t = blockIdx.x * 256 + threadIdx.x;
  if (t >= TOT) return;
  int e = t / NE, m = t - e * NE;
  int tgt;
  if (e < 3) tgt = edges[(e * NE + m) * 2 + 1];
  else       tgt = edges[((e - 3) * NE + m) * 2];
  atomicAdd(&cnt6[tgt * 6 + e], 1);
}

__global__ __launch_bounds__(256) void k_div(const int* __restrict__ cnt6,
    float* __restrict__ divf) {
  int i = blockIdx.x * 256 + threadIdx.x;
  if (i < NP) {
    int c = 0;
#pragma unroll
    for (int e = 0; e < 6; e++) c += cnt6[i * 6 + e];
    divf[i] = c ? (float)c : 1.0f;
  }
}

// exclusive scan over cnt6 (length L6P) -> offs6
__global__ __launch_bounds__(256) void k_scan1(const int* __restrict__ cnt, int* __restrict__ bsum) {
  int base = blockIdx.x * SCHUNK + threadIdx.x * 8;
  int s = 0;
#pragma unroll
  for (int j = 0; j < 8; j++) { int idx = base + j; s += (idx < L6P) ? cnt[idx] : 0; }
  for (int o = 32; o > 0; o >>= 1) s += __shfl_down(s, o);
  __shared__ int sm[4];
  if ((threadIdx.x & 63) == 0) sm[threadIdx.x >> 6] = s;
  __syncthreads();
  if (threadIdx.x == 0) bsum[blockIdx.x] = sm[0] + sm[1] + sm[2] + sm[3];
}

__global__ __launch_bounds__(512) void k_scan2(int* __restrict__ bsum, int nb) { // 1 block, nb<=512
  int t = threadIdx.x, lane = t & 63, wv = t >> 6;
  int orig = (t < nb) ? bsum[t] : 0;
  int v = orig;
  for (int o = 1; o < 64; o <<= 1) { int x = __shfl_up(v, o); if (lane >= o) v += x; }
  __shared__ int ws[8];
  if (lane == 63) ws[wv] = v;
  __syncthreads();
  int add = 0;
  for (int w = 0; w < wv; w++) add += ws[w];
  if (t < nb) bsum[t] = v - orig + add;   // exclusive
}

__global__ __launch_bounds__(256) void k_scan3(const int* __restrict__ cnt,
    const int* __restrict__ bsum, int* __restrict__ offs) {
  int base = blockIdx.x * SCHUNK + threadIdx.x * 8;
  int vals[8], pre[8];
  int s = 0;
#pragma unroll
  for (int j = 0; j < 8; j++) {
    int idx = base + j;
    vals[j] = (idx < L6P) ? cnt[idx] : 0;
    pre[j] = s; s += vals[j];
  }
  int lane = threadIdx.x & 63, wvi = threadIdx.x >> 6;
  int v = s;
  for (int o = 1; o < 64; o <<= 1) { int t = __shfl_up(v, o); if (lane >= o) v += t; }
  __shared__ int wsum[4];
  if (lane == 63) wsum[wvi] = v;
  __syncthreads();
  int wpre = 0;
  for (int w = 0; w < wvi; w++) wpre += wsum[w];
  int texcl = (v - s) + wpre + bsum[blockIdx.x];
#pragma unroll
  for (int j = 0; j < 8; j++) {
    int idx = base + j;
    if (idx < L6P) {
      offs[idx] = texcl + pre[j];
      if (idx == L6P - 1) offs[L6P] = texcl + pre[j] + vals[j];
    }
  }
}

// direct CSR fill (cursor atomics spread over 600k addresses)
__global__ __launch_bounds__(256) void k_fill(const int* __restrict__ edges,
    int* __restrict__ cursor6, int* __restrict__ entries) {
  int t = blockIdx.x * 256 + threadIdx.x;
  if (t >= TOT) return;
  int e = t / NE, m = t - e * NE;
  int src, tgt;
  if (e < 3) { int b = (e * NE + m) * 2;       src = edges[b];     tgt = edges[b + 1]; }
  else       { int b = ((e - 3) * NE + m) * 2; src = edges[b + 1]; tgt = edges[b]; }
  int pos = atomicAdd(&cursor6[tgt * 6 + e], 1);
  entries[pos] = src;   // type implied by segment
}

// ---------- per-layer kernels ----------

// Wave-per-node aggregation: one coalesced 64-entry preload covers the whole
// node (avg deg 24); 6 type-segments walked as uniform sub-loops over the
// preloaded register (readlane -> SALU addr); 4-deep clamped gather unroll.
__global__ __launch_bounds__(512) void k_agg(const ushort_t* __restrict__ hbf,
    const int* __restrict__ offs6, const int* __restrict__ entries,
    ushort_t* __restrict__ agg, int node0, int rows) {
  int lane = threadIdx.x & 63, wv = threadIdx.x >> 6;
  int rloc = blockIdx.x * 8 + wv;
  if (rloc >= rows) return;
  int n = node0 + rloc;
  uint_t* outp = (uint_t*)(agg + (size_t)rloc * 768);
  int voff = lane * 4;
  const char* hb = (const char*)hbf;
  int bj = offs6[n * 6 + (lane < 6 ? lane : 6)];   // lane j: S[min(j,6)]
  int S0    = __builtin_amdgcn_readlane(bj, 0);
  int Send  = __builtin_amdgcn_readlane(bj, 6);
  int total = Send - S0;
  int curC = 0;
  int ent = (total > 0) ? entries[S0 + (lane < total ? lane : total - 1)] : 0;
  for (int e = 0; e < 6; e++) {
    float cx = 0.f, cy = 0.f;
    int E = __builtin_amdgcn_readlane(bj, e + 1) - S0;
    int j = __builtin_amdgcn_readlane(bj, e) - S0;
    while (j < E) {
      if (j >= curC + 64) {               // uniform: advance preload chunk
        curC += 64;
        int rem = total - curC;
        ent = entries[S0 + curC + (lane < rem ? lane : rem - 1)];
        continue;
      }
      int upto = E < curC + 64 ? E : curC + 64;
      for (; j < upto; j += 4) {          // 4-deep clamped: parallel load issue
        int s_[4]; uint_t v[4];
#pragma unroll
        for (int u = 0; u < 4; u++) {
          int jj = (j + u < upto) ? j + u : upto - 1;
          s_[u] = __builtin_amdgcn_readlane(ent, jj - curC);
        }
#pragma unroll
        for (int u = 0; u < 4; u++)
          v[u] = *(const uint_t*)(hb + ((size_t)(uint_t)s_[u] << 8) + voff);
        cx += bflo(v[0]); cy += bfhi(v[0]);
#pragma unroll
        for (int u = 1; u < 4; u++)
          if (j + u < upto) { cx += bflo(v[u]); cy += bfhi(v[u]); }
      }
    }
    outp[e * 64 + lane] = packbf(cx, cy);  // pads/empty segments write zeros
  }
}

// Fused msgs-GEMM + GRU. Block = 128 nodes, 8 waves, 64KB LDS.
// Phase A: msgs = (agg@Wcat + sum_e cnt_e*b_msg_e)/div + 1e-8 -> swizzled Mlds.
// Phase B: gates = [msgs|h] x [wih|whh], GRU math, write new h (bf16) to hbfout.
// All LDS tiles XOR-swizzled (byte ^= (row&7)<<4); gload_lds uses pre-swizzled src.
__global__ __launch_bounds__(512, 2) void k_fused(
    const ushort_t* __restrict__ agg, const ushort_t* __restrict__ Wcat,
    const int* __restrict__ cnt6, const float* __restrict__ divf,
    const float* __restrict__ b_msg, const ushort_t* __restrict__ hbfin,
    const ushort_t* __restrict__ wihb, const ushort_t* __restrict__ whhb,
    const float* __restrict__ b_ih, const float* __restrict__ b_hh,
    float* __restrict__ hf, ushort_t* __restrict__ hbfout,
    int node0, int last) {
  __shared__ char smem[65536];
  char* Alds = smem;             // 16KB (phase A), 128 rows x 128B
  char* Blds = smem + 16384;     // 16KB (phase A)
  char* Mlds = smem + 32768;     // 32KB msgs tile, 128 rows x 256B
  char* Hlds = smem;             // 32KB h tile (phase B, reuses A/B)
  int lane = threadIdx.x & 63, wv = threadIdx.x >> 6;
  int wr = wv >> 1, wc = wv & 1;
  int rbase = blockIdx.x * 128;

  // ---- phase A ----
  f32x4 acc[2][4] = {};
  for (int k0 = 0; k0 < 768; k0 += 64) {
#pragma unroll
    for (int i = 0; i < 2; i++) {
      int base = i * 8192 + wv * 1024;
      int q = base + lane * 16;
      int row = q >> 7;
      int colb = (q & 127) ^ ((row & 7) << 4);
      GLOAD_LDS16(agg + (size_t)(rbase + row) * 768 + k0 + (colb >> 1), Alds + base);
      GLOAD_LDS16(Wcat + (size_t)row * 768 + k0 + (colb >> 1), Blds + base);
    }
    __syncthreads();
#pragma unroll
    for (int kk = 0; kk < 2; kk++) {
      bf16x8 af[2], bv[4];
#pragma unroll
      for (int m = 0; m < 2; m++) {
        int row = wr * 32 + m * 16 + (lane & 15);
        int b = ((row << 7) + kk * 64 + ((lane >> 4) << 4)) ^ ((row & 7) << 4);
        af[m] = *(const bf16x8*)(Alds + b);
      }
#pragma unroll
      for (int nf = 0; nf < 4; nf++) {
        int row = wc * 64 + nf * 16 + (lane & 15);
        int b = ((row << 7) + kk * 64 + ((lane >> 4) << 4)) ^ ((row & 7) << 4);
        bv[nf] = *(const bf16x8*)(Blds + b);
      }
#pragma unroll
      for (int m = 0; m < 2; m++)
#pragma unroll
        for (int nf = 0; nf < 4; nf++)
          acc[m][nf] = mfma16(af[m], bv[nf], acc[m][nf]);
    }
    __syncthreads();
  }
  // issue h-tile staging (overwrites Alds/Blds; all phase-A reads are done)
#pragma unroll
  for (int i = 0; i < 4; i++) {
    int base = i * 8192 + wv * 1024;
    int q = base + lane * 16;
    int row = q >> 8;
    int colb = (q & 255) ^ ((row & 7) << 4);
    GLOAD_LDS16(hbfin + (size_t)(node0 + rbase + row) * HD + (colb >> 1), Hlds + base);
  }
  // epilogue: msgs -> Mlds (swizzled); overlaps the h-tile load latency
#pragma unroll
  for (int m = 0; m < 2; m++) {
#pragma unroll
    for (int r = 0; r < 4; r++) {
      int rloc = wr * 32 + m * 16 + (lane >> 4) * 4 + r;
      int node = node0 + rbase + rloc;   // divf/cnt6 are NP-sized: pads -> c=0, div=1
      float dv = divf[node];
      const int* c6 = cnt6 + (size_t)node * 6;
      int c[6];
#pragma unroll
      for (int e = 0; e < 6; e++) c[e] = c6[e];
#pragma unroll
      for (int nf = 0; nf < 4; nf++) {
        int col = wc * 64 + nf * 16 + (lane & 15);
        float badd = 0.f;
#pragma unroll
        for (int e = 0; e < 6; e++) badd += (float)c[e] * b_msg[e * 128 + col];
        float v = (acc[m][nf][r] + badd) / dv + 1e-8f;
        int b = ((rloc << 8) + col * 2) ^ ((rloc & 7) << 4);
        *(ushort_t*)(Mlds + b) = f2bf(v);
      }
    }
  }
  __syncthreads();   // Mlds visible + Hlds loaded (vmcnt drained at barrier)

  // ---- phase B: GRU, 4 rounds x 32 rows ----
  int d = wv * 16 + (lane & 15);
  float bir = b_ih[d],       bhr = b_hh[d];
  float biz = b_ih[128 + d], bhz = b_hh[128 + d];
  float bin = b_ih[256 + d], bhn = b_hh[256 + d];
#pragma unroll
  for (int rd = 0; rd < 4; rd++) {
    f32x4 acb[2][6] = {};
#pragma unroll
    for (int ks = 0; ks < 4; ks++) {
      bf16x8 am[2], ah[2];
#pragma unroll
      for (int m = 0; m < 2; m++) {
        int row = rd * 32 + m * 16 + (lane & 15);
        int b = ((row << 8) + ks * 64 + ((lane >> 4) << 4)) ^ ((row & 7) << 4);
        am[m] = *(const bf16x8*)(Mlds + b);
        ah[m] = *(const bf16x8*)(Hlds + b);
      }
      bf16x8 bi[3], bh[3];
#pragma unroll
      for (int g = 0; g < 3; g++) {
        int nidx = g * 128 + d;
        int ko = ks * 32 + ((lane >> 4) << 3);
        bi[g] = *(const bf16x8*)(wihb + (size_t)nidx * HD + ko);
        bh[g] = *(const bf16x8*)(whhb + (size_t)nidx * HD + ko);
      }
#pragma unroll
      for (int m = 0; m < 2; m++)
#pragma unroll
        for (int g = 0; g < 3; g++) {
          acb[m][g]     = mfma16(am[m], bi[g], acb[m][g]);
          acb[m][3 + g] = mfma16(ah[m], bh[g], acb[m][3 + g]);
        }
    }
#pragma unroll
    for (int m = 0; m < 2; m++) {
#pragma unroll
      for (int r = 0; r < 4; r++) {
        int rloc = rd * 32 + m * 16 + (lane >> 4) * 4 + r;
        int row = node0 + rbase + rloc;
        if (row < NN) {
          float ir = acb[m][0][r], iz = acb[m][1][r], in = acb[m][2][r];
          float hr = acb[m][3][r], hz = acb[m][4][r], hn = acb[m][5][r];
          float rg = 1.f / (1.f + expf(-(ir + hr + bir + bhr)));
          float zg = 1.f / (1.f + expf(-(iz + hz + biz + bhz)));
          float ng = tanhf(in + bin + rg * (hn + bhn));
          int hb = ((rloc << 8) + d * 2) ^ ((rloc & 7) << 4);
          float hold = bf2f(*(const ushort_t*)(Hlds + hb));
          float o = (1.f - zg) * ng + zg * hold;
          size_t idx = (size_t)row * HD + d;
          hbfout[idx] = f2bf(o);
          if (last) hf[idx] = o;
        }
      }
    }
  }
}

// ---------- host ----------

extern "C" void kernel_launch(void* const* d_in, const int* in_sizes, int n_in,
                              void* d_out, int out_size, void* d_ws, size_t ws_size,
                              hipStream_t stream) {
  const float* node_states = (const float*)d_in[0];
  const int*   edges       = (const int*)d_in[1];
  const float* W_msg       = (const float*)d_in[2];
  const float* b_msg       = (const float*)d_in[3];
  const float* w_ih        = (const float*)d_in[4];
  const float* w_hh        = (const float*)d_in[5];
  const float* b_ih        = (const float*)d_in[6];
  const float* b_hh        = (const float*)d_in[7];
  float* out_h   = (float*)d_out;
  float* out_old = out_h + (size_t)NN * HD;

  char* p = (char*)d_ws;
  auto carve = [&](size_t bytes) { char* r = p; p += (bytes + 255) & ~(size_t)255; return r; };
  ushort_t* hbfA  = (ushort_t*)carve((size_t)NP * HD * 2);
  ushort_t* hbfB  = (ushort_t*)carve((size_t)NP * HD * 2);
  ushort_t* Wcat  = (ushort_t*)carve((size_t)128 * 768 * 2);
  ushort_t* wihb  = (ushort_t*)carve((size_t)384 * 128 * 2);
  ushort_t* whhb  = (ushort_t*)carve((size_t)384 * 128 * 2);
  int*   cnt6     = (int*)carve((size_t)L6P * 4);
  float* divf     = (float*)carve((size_t)NP * 4);
  int*   offs6    = (int*)carve((size_t)(L6P + 1) * 4);
  int*   cursor6  = (int*)carve((size_t)L6P * 4);
  int*   entries  = (int*)carve((size_t)TOT * 4);
  int*   bsum     = (int*)carve(512 * 4);
  size_t used  = (size_t)(p - (char*)d_ws);
  size_t avail = ws_size > used ? ws_size - used : 0;
  size_t chunk_rows = avail / (768 * 2);
  if (chunk_rows > (size_t)CHROWS) chunk_rows = CHROWS;   // keep agg chunk L3-resident
  chunk_rows &= ~(size_t)127;
  if (chunk_rows < 128) chunk_rows = 128;
  ushort_t* agg = (ushort_t*)p;

  hipMemsetAsync(cnt6, 0, (size_t)L6P * 4, stream);
  hipMemsetAsync(hbfA + (size_t)NN * HD, 0, (size_t)(NP - NN) * HD * 2, stream);
  hipMemsetAsync(hbfB + (size_t)NN * HD, 0, (size_t)(NP - NN) * HD * 2, stream);

  k_init<<<(NN * HD + 255) / 256, 256, 0, stream>>>(node_states, out_h, out_old, hbfA);
  k_prep<<<(128 * 768 + 255) / 256, 256, 0, stream>>>(W_msg, w_ih, w_hh, Wcat, wihb, whhb);
  k_hist<<<(TOT + 255) / 256, 256, 0, stream>>>(edges, cnt6);
  k_div<<<(NP + 255) / 256, 256, 0, stream>>>(cnt6, divf);
  int nb = (L6P + SCHUNK - 1) / SCHUNK;   // 294
  k_scan1<<<nb, 256, 0, stream>>>(cnt6, bsum);
  k_scan2<<<1, 512, 0, stream>>>(bsum, nb);
  k_scan3<<<nb, 256, 0, stream>>>(cnt6, bsum, offs6);
  hipMemcpyAsync(cursor6, offs6, (size_t)L6P * 4, hipMemcpyDeviceToDevice, stream);
  k_fill<<<(TOT + 255) / 256, 256, 0, stream>>>(edges, cursor6, entries);

  ushort_t* hA = hbfA;
  ushort_t* hB = hbfB;
  for (int L = 0; L < NLAYER; L++) {
    int last = (L == NLAYER - 1);
    for (size_t n0 = 0; n0 < (size_t)NP; n0 += chunk_rows) {
      int rows = (int)(((size_t)NP - n0) < chunk_rows ? ((size_t)NP - n0) : chunk_rows);
      k_agg<<<(rows + 7) / 8, 512, 0, stream>>>(hA, offs6, entries, agg, (int)n0, rows);
      k_fused<<<rows / 128, 512, 0, stream>>>(agg, Wcat, cnt6, divf, b_msg, hA,
                                              wihb, whhb, b_ih, b_hh,
                                              out_h, hB, (int)n0, last);
    }
    ushort_t* tmp = hA; hA = hB; hB = tmp;
  }
}